// Round 6
// baseline (351.661 us; speedup 1.0000x reference)
//
#include <hip/hip_runtime.h>
#include <hip/hip_bf16.h>

#define NN 100000
#define EE 1600000
#define CH 64
#define ED 16
#define HID 32
#define NBKT 1563    // ceil(NN/64); bucket = col >> 6 (64 nodes per bucket)
#define NPAIR 782    // ceil(NBKT/2) packed u16 count pairs
#define BCAP 1216    // bucket capacity: mean 1024, +6 sigma

__device__ __forceinline__ float sigm(float x) {
    return __builtin_amdgcn_rcpf(1.0f + __expf(-x));
}

// Hardware LDS f32 atomic add via inline asm (compiler FP atomics on LDS lower
// to CAS loops: R1/R2). asm DS ops are invisible to SIInsertWaitcnts -- caller
// MUST drain lgkmcnt before any barrier publishing the results (R3 lesson).
__device__ __forceinline__ void lds_fadd(float* p, float v) {
    asm volatile("ds_add_f32 %0, %1"
                 :: "v"((unsigned)(unsigned long long)p), "v"(v));
}

// K1: fused edge-MLP gate + coarse binning. Block = 4096 edges, 512 threads.
// LDS slimmed 45.6->19.5 KB (R5: occupancy was 24.6%, 1 block/CU):
//  - counts packed u16 pairs (totals <= ~1300 << 65536, no cross-half carry)
//  - base merged into hist (pass-2 packed atomicAdd returns base+rank)
//  - scol dropped (pass 2 re-reads ei col; L3-resident)
__global__ void __launch_bounds__(512) gate_bin_kernel(
    const float* __restrict__ ea,
    const float* __restrict__ W1, const float* __restrict__ b1,
    const float* __restrict__ W2, const float* __restrict__ b2,
    const int* __restrict__ ei,
    int* __restrict__ gcursor, unsigned long long* __restrict__ binned)
{
    __shared__ unsigned hist[NPAIR];   // 3.13 KB: packed {lo16,hi16} counts/bases
    __shared__ float    sal[4096];     // 16 KB
    int t = threadIdx.x;
    for (int i = t; i < NPAIR; i += 512) hist[i] = 0;
    __syncthreads();
    int e0 = blockIdx.x * 4096;
#pragma unroll 1
    for (int k = 0; k < 8; k++) {
        int idx = k * 512 + t;
        int e = e0 + idx;
        if (e < EE) {
            const float4* p = (const float4*)(ea + (size_t)e * ED);
            float4 q0 = p[0], q1 = p[1], q2 = p[2], q3 = p[3];
            float a[ED] = {q0.x, q0.y, q0.z, q0.w, q1.x, q1.y, q1.z, q1.w,
                           q2.x, q2.y, q2.z, q2.w, q3.x, q3.y, q3.z, q3.w};
            float acc = b2[0];
#pragma unroll
            for (int j = 0; j < HID; j++) {
                float hj = b1[j];
#pragma unroll
                for (int kk = 0; kk < ED; kk++) hj = fmaf(a[kk], W1[kk * HID + j], hj);
                hj *= sigm(hj);
                acc = fmaf(hj, W2[j], acc);
            }
            sal[idx] = sigm(acc);
            int bkt = ei[EE + e] >> 6;
            atomicAdd(&hist[bkt >> 1], 1u << (16 * (bkt & 1)));  // native ds_add_u32
        }
    }
    __syncthreads();
    for (int i = t; i < NPAIR; i += 512) {
        unsigned h = hist[i];
        unsigned c0 = h & 0xFFFFu, c1 = h >> 16;
        unsigned b0 = c0 ? (unsigned)atomicAdd(&gcursor[2 * i], (int)c0) : 0u;
        unsigned b1v = c1 ? (unsigned)atomicAdd(&gcursor[2 * i + 1], (int)c1) : 0u;
        hist[i] = b0 | (b1v << 16);    // hist now holds packed bases
    }
    __syncthreads();
#pragma unroll 1
    for (int k = 0; k < 8; k++) {
        int idx = k * 512 + t;
        int e = e0 + idx;
        if (e < EE) {
            int row = ei[e];
            int cv = ei[EE + e];
            float alv = sal[idx];
            int bkt = cv >> 6;
            unsigned old = atomicAdd(&hist[bkt >> 1], 1u << (16 * (bkt & 1)));
            int slot = (int)((old >> (16 * (bkt & 1))) & 0xFFFFu);  // base+rank
            if (slot < BCAP)
                binned[(size_t)bkt * BCAP + slot] =
                    ((unsigned long long)__float_as_uint(alv) << 32)
                    | (unsigned)(row | ((cv & 63) << 17));
        }
    }
}

// K2: per-bucket node-sort into CSR (integer-only ranking). Also computes
// per-node alpha-sum -> dis, and nrange[node] = {start,end}.
__global__ void __launch_bounds__(256) place_kernel(
    const unsigned long long* __restrict__ binned, const int* __restrict__ gcursor,
    int2* __restrict__ nrange, float* __restrict__ dis, float2* __restrict__ csr)
{
    __shared__ int   cnt[64];
    __shared__ float nsum[64];
    __shared__ int   rk[64];
    __shared__ int   start[64];
    int t = threadIdx.x;
    int bkt = blockIdx.x;
    int size = gcursor[bkt];
    if (size > BCAP) size = BCAP;
    if (t < 64) { cnt[t] = 0; nsum[t] = 0.0f; rk[t] = 0; }
    __syncthreads();
    const unsigned long long* bb = binned + (size_t)bkt * BCAP;
    for (int i = t; i < size; i += 256) {
        unsigned long long p = bb[i];
        unsigned lo = (unsigned)p;
        int cl = (lo >> 17) & 63;
        atomicAdd(&cnt[cl], 1);                       // native ds_add_u32
        lds_fadd(&nsum[cl], __uint_as_float((unsigned)(p >> 32)));
    }
    // drain asm ds_adds before the barrier publishes nsum (R3 lesson)
    asm volatile("s_waitcnt lgkmcnt(0)" ::: "memory");
    __syncthreads();
    if (t < 64) {                                     // wave 0: 64-wide scan
        int orig = cnt[t];
        int v = orig;
#pragma unroll
        for (int off = 1; off < 64; off <<= 1) {
            int u = __shfl_up(v, off, 64);
            if (t >= off) v += u;
        }
        int excl = v - orig;
        int s = bkt * BCAP + excl;
        start[t] = s;
        int node = bkt * 64 + t;
        if (node < NN) {
            nrange[node] = make_int2(s, s + orig);
            float d = nsum[t];
            dis[node] = (d > 0.0f) ? rsqrtf(d) : 0.0f;
        }
    }
    __syncthreads();
    for (int i = t; i < size; i += 256) {
        unsigned long long p = bb[i];
        unsigned lo = (unsigned)p;
        int cl = (lo >> 17) & 63;
        int row = lo & 0x1FFFF;
        int r = atomicAdd(&rk[cl], 1);                // native ds_add_rtn_u32
        csr[start[cl] + r] =
            make_float2(__int_as_float(row), __uint_as_float((unsigned)(p >> 32)));
    }
}

// K3: xwh = bf16( (x @ W) * dis[row] ). 32 rows/block; runs after place_kernel
// (needs dis). Folding dis[row] here removes the per-edge dis gather entirely.
__global__ void __launch_bounds__(256) xw_kernel(
    const float* __restrict__ x, const float* __restrict__ W,
    const float* __restrict__ dis, __hip_bfloat16* __restrict__ xwh)
{
    __shared__ float sW[CH * CH];   // 16 KB
    __shared__ float sx[32][CH];    // 8 KB
    int t = threadIdx.x;
    for (int i = t; i < CH * CH; i += 256) sW[i] = W[i];
    for (int i = t; i < 32 * CH; i += 256)
        sx[i >> 6][i & 63] = x[(size_t)blockIdx.x * (32 * CH) + i];
    __syncthreads();
    int rr = t >> 6, cc = t & 63;
    float a[8] = {0.f, 0.f, 0.f, 0.f, 0.f, 0.f, 0.f, 0.f};
    for (int k = 0; k < CH; k += 4) {
        float w0 = sW[k * CH + cc],       w1 = sW[(k + 1) * CH + cc];
        float w2 = sW[(k + 2) * CH + cc], w3 = sW[(k + 3) * CH + cc];
#pragma unroll
        for (int j = 0; j < 8; j++) {
            float4 xv = *(const float4*)&sx[rr + 4 * j][k];
            a[j] = fmaf(xv.x, w0, a[j]);
            a[j] = fmaf(xv.y, w1, a[j]);
            a[j] = fmaf(xv.z, w2, a[j]);
            a[j] = fmaf(xv.w, w3, a[j]);
        }
    }
    int r0 = blockIdx.x * 32;
#pragma unroll
    for (int j = 0; j < 8; j++) {
        int r = r0 + rr + 4 * j;
        xwh[(size_t)r * CH + cc] = __float2bfloat16(a[j] * dis[r]);
    }
}

// K4: R0's harness-proven gather structure: one wave per node, lane = channel,
// register accumulation over the node's contiguous CSR slice, 4-edge ILP,
// then LN + SiLU + residual. No LDS, no barriers.
__global__ void __launch_bounds__(256) gather_finalize_kernel(
    const float2* __restrict__ csr, const int2* __restrict__ nrange,
    const float* __restrict__ dis, const __hip_bfloat16* __restrict__ xwh,
    const float* __restrict__ x, const float* __restrict__ b,
    const float* __restrict__ gamma, const float* __restrict__ beta,
    float* __restrict__ out)
{
    int t = threadIdx.x;
    int node = blockIdx.x * 4 + (t >> 6);
    int c = t & 63;
    int2 rg = nrange[node];
    int s = rg.x, en = rg.y;
    float acc = 0.0f;
    int i = s;
    if ((i & 1) && i < en) {
        float2 p = csr[i++];
        int r = __float_as_int(p.x);
        acc = fmaf(__bfloat162float(xwh[(size_t)r * CH + c]), p.y, acc);
    }
    for (; i + 3 < en; i += 4) {
        float4 q0 = *(const float4*)(csr + i);
        float4 q1 = *(const float4*)(csr + i + 2);
        int r0 = __float_as_int(q0.x), r1 = __float_as_int(q0.z);
        int r2 = __float_as_int(q1.x), r3 = __float_as_int(q1.z);
        acc = fmaf(__bfloat162float(xwh[(size_t)r0 * CH + c]), q0.y, acc);
        acc = fmaf(__bfloat162float(xwh[(size_t)r1 * CH + c]), q0.w, acc);
        acc = fmaf(__bfloat162float(xwh[(size_t)r2 * CH + c]), q1.y, acc);
        acc = fmaf(__bfloat162float(xwh[(size_t)r3 * CH + c]), q1.w, acc);
    }
    if (i + 1 < en) {
        float4 q0 = *(const float4*)(csr + i);
        int r0 = __float_as_int(q0.x), r1 = __float_as_int(q0.z);
        acc = fmaf(__bfloat162float(xwh[(size_t)r0 * CH + c]), q0.y, acc);
        acc = fmaf(__bfloat162float(xwh[(size_t)r1 * CH + c]), q0.w, acc);
        i += 2;
    }
    if (i < en) {
        float2 p = csr[i];
        int r = __float_as_int(p.x);
        acc = fmaf(__bfloat162float(xwh[(size_t)r * CH + c]), p.y, acc);
    }
    float hv = fmaf(acc, dis[node], b[c]);
    float ssum = hv;
#pragma unroll
    for (int off = 32; off; off >>= 1) ssum += __shfl_xor(ssum, off, 64);
    float mu = ssum * (1.0f / 64.0f);
    float d = hv - mu;
    float v2 = d * d;
#pragma unroll
    for (int off = 32; off; off >>= 1) v2 += __shfl_xor(v2, off, 64);
    float y = d * rsqrtf(v2 * (1.0f / 64.0f) + 1e-5f) * gamma[c] + beta[c];
    y *= sigm(y);
    size_t idx = (size_t)node * CH + c;
    out[idx] = y + x[idx];
}

extern "C" void kernel_launch(void* const* d_in, const int* in_sizes, int n_in,
                              void* d_out, int out_size, void* d_ws, size_t ws_size,
                              hipStream_t stream)
{
    const float* x     = (const float*)d_in[0];
    const int*   ei    = (const int*)d_in[1];
    const float* ea    = (const float*)d_in[2];
    const float* W     = (const float*)d_in[3];
    const float* b     = (const float*)d_in[4];
    const float* W1    = (const float*)d_in[5];
    const float* b1    = (const float*)d_in[6];
    const float* W2    = (const float*)d_in[7];
    const float* b2    = (const float*)d_in[8];
    const float* gamma = (const float*)d_in[9];
    const float* beta  = (const float*)d_in[10];
    float* out = (float*)d_out;

    // ws layout: binned u64[NBKT*BCAP] | csr f2[NBKT*BCAP] | xwh bf16[NN*CH]
    //            | nrange int2[NN] | dis f32[NN] | gcursor i32[NBKT+1 pad]
    unsigned long long* binned = (unsigned long long*)d_ws;
    float2* csr    = (float2*)(binned + (size_t)NBKT * BCAP);
    __hip_bfloat16* xwh = (__hip_bfloat16*)(csr + (size_t)NBKT * BCAP);
    int2*  nrange  = (int2*)(xwh + (size_t)NN * CH);
    float* dis     = (float*)(nrange + NN);
    int*   gcursor = (int*)(dis + NN);

    hipMemsetAsync(gcursor, 0, (NBKT + 1) * sizeof(int), stream);

    gate_bin_kernel<<<(EE + 4095) / 4096, 512, 0, stream>>>(ea, W1, b1, W2, b2, ei,
                                                            gcursor, binned);
    place_kernel<<<NBKT, 256, 0, stream>>>(binned, gcursor, nrange, dis, csr);
    xw_kernel<<<NN / 32, 256, 0, stream>>>(x, W, dis, xwh);
    gather_finalize_kernel<<<NN / 4, 256, 0, stream>>>(csr, nrange, dis, xwh,
                                                       x, b, gamma, beta, out);
}

// Round 7
// 346.030 us; speedup vs baseline: 1.0163x; 1.0163x over previous
//
#include <hip/hip_runtime.h>
#include <hip/hip_bf16.h>

#define NN 100000
#define EE 1600000
#define CH 64
#define ED 16
#define HID 32
#define NBKT 1563    // ceil(NN/64); bucket = col >> 6 (64 nodes per bucket)
#define NPAIR 782    // ceil(NBKT/2) packed u16 count pairs
#define BCAP 1216    // bucket capacity: mean 1024, +6 sigma
#define EPB 2048     // edges per gate_bin block (782 blocks: grid was the R5/R6
                     // occupancy cap at 391 blocks / 256 CUs)

__device__ __forceinline__ float sigm(float x) {
    return __builtin_amdgcn_rcpf(1.0f + __expf(-x));
}

// Hardware LDS f32 atomic add via inline asm (compiler FP atomics on LDS lower
// to CAS loops: R1/R2). asm DS ops are invisible to SIInsertWaitcnts -- caller
// MUST drain lgkmcnt before any barrier publishing the results (R3 lesson).
__device__ __forceinline__ void lds_fadd(float* p, float v) {
    asm volatile("ds_add_f32 %0, %1"
                 :: "v"((unsigned)(unsigned long long)p), "v"(v));
}

// K1: fused edge-MLP gate + coarse binning. 512 thr x 2048 edges -> 782 blocks
// (R7: grid parallelism was the bottleneck, not LDS). alpha+col staged in LDS
// between passes; counts packed u16 (totals <= 2048 << 65536, no carry);
// base merged into hist (pass-2 packed atomicAdd returns base+rank).
__global__ void __launch_bounds__(512) gate_bin_kernel(
    const float* __restrict__ ea,
    const float* __restrict__ W1, const float* __restrict__ b1,
    const float* __restrict__ W2, const float* __restrict__ b2,
    const int* __restrict__ ei,
    int* __restrict__ gcursor, unsigned long long* __restrict__ binned)
{
    __shared__ unsigned hist[NPAIR];   // 3.13 KB packed counts -> bases
    __shared__ float    sal[EPB];      // 8 KB
    __shared__ int      scol[EPB];     // 8 KB
    int t = threadIdx.x;
    for (int i = t; i < NPAIR; i += 512) hist[i] = 0;
    __syncthreads();
    int e0 = blockIdx.x * EPB;
#pragma unroll 1
    for (int k = 0; k < EPB / 512; k++) {
        int idx = k * 512 + t;
        int e = e0 + idx;
        if (e < EE) {
            const float4* p = (const float4*)(ea + (size_t)e * ED);
            float4 q0 = p[0], q1 = p[1], q2 = p[2], q3 = p[3];
            float a[ED] = {q0.x, q0.y, q0.z, q0.w, q1.x, q1.y, q1.z, q1.w,
                           q2.x, q2.y, q2.z, q2.w, q3.x, q3.y, q3.z, q3.w};
            float acc = b2[0];
#pragma unroll
            for (int j = 0; j < HID; j++) {
                float hj = b1[j];
#pragma unroll
                for (int kk = 0; kk < ED; kk++) hj = fmaf(a[kk], W1[kk * HID + j], hj);
                hj *= sigm(hj);
                acc = fmaf(hj, W2[j], acc);
            }
            float alv = sigm(acc);
            int cv = ei[EE + e];
            sal[idx] = alv;
            scol[idx] = cv;
            int bkt = cv >> 6;
            atomicAdd(&hist[bkt >> 1], 1u << (16 * (bkt & 1)));  // native ds_add_u32
        }
    }
    __syncthreads();
    for (int i = t; i < NPAIR; i += 512) {
        unsigned h = hist[i];
        unsigned c0 = h & 0xFFFFu, c1 = h >> 16;
        unsigned b0 = c0 ? (unsigned)atomicAdd(&gcursor[2 * i], (int)c0) : 0u;
        unsigned b1v = c1 ? (unsigned)atomicAdd(&gcursor[2 * i + 1], (int)c1) : 0u;
        hist[i] = b0 | (b1v << 16);    // hist now holds packed bases
    }
    __syncthreads();
#pragma unroll 1
    for (int k = 0; k < EPB / 512; k++) {
        int idx = k * 512 + t;
        int e = e0 + idx;
        if (e < EE) {
            int row = ei[e];
            int cv = scol[idx];
            float alv = sal[idx];
            int bkt = cv >> 6;
            unsigned old = atomicAdd(&hist[bkt >> 1], 1u << (16 * (bkt & 1)));
            int slot = (int)((old >> (16 * (bkt & 1))) & 0xFFFFu);  // base+rank
            if (slot < BCAP)
                binned[(size_t)bkt * BCAP + slot] =
                    ((unsigned long long)__float_as_uint(alv) << 32)
                    | (unsigned)(row | ((cv & 63) << 17));
        }
    }
}

// K2: per-bucket node-sort into CSR (integer-only ranking). Also computes
// per-node alpha-sum -> dis, and nrange[node] = {start,end}.
__global__ void __launch_bounds__(256) place_kernel(
    const unsigned long long* __restrict__ binned, const int* __restrict__ gcursor,
    int2* __restrict__ nrange, float* __restrict__ dis, float2* __restrict__ csr)
{
    __shared__ int   cnt[64];
    __shared__ float nsum[64];
    __shared__ int   rk[64];
    __shared__ int   start[64];
    int t = threadIdx.x;
    int bkt = blockIdx.x;
    int size = gcursor[bkt];
    if (size > BCAP) size = BCAP;
    if (t < 64) { cnt[t] = 0; nsum[t] = 0.0f; rk[t] = 0; }
    __syncthreads();
    const unsigned long long* bb = binned + (size_t)bkt * BCAP;
    for (int i = t; i < size; i += 256) {
        unsigned long long p = bb[i];
        unsigned lo = (unsigned)p;
        int cl = (lo >> 17) & 63;
        atomicAdd(&cnt[cl], 1);                       // native ds_add_u32
        lds_fadd(&nsum[cl], __uint_as_float((unsigned)(p >> 32)));
    }
    // drain asm ds_adds before the barrier publishes nsum (R3 lesson)
    asm volatile("s_waitcnt lgkmcnt(0)" ::: "memory");
    __syncthreads();
    if (t < 64) {                                     // wave 0: 64-wide scan
        int orig = cnt[t];
        int v = orig;
#pragma unroll
        for (int off = 1; off < 64; off <<= 1) {
            int u = __shfl_up(v, off, 64);
            if (t >= off) v += u;
        }
        int excl = v - orig;
        int s = bkt * BCAP + excl;
        start[t] = s;
        int node = bkt * 64 + t;
        if (node < NN) {
            nrange[node] = make_int2(s, s + orig);
            float d = nsum[t];
            dis[node] = (d > 0.0f) ? rsqrtf(d) : 0.0f;
        }
    }
    __syncthreads();
    for (int i = t; i < size; i += 256) {
        unsigned long long p = bb[i];
        unsigned lo = (unsigned)p;
        int cl = (lo >> 17) & 63;
        int row = lo & 0x1FFFF;
        int r = atomicAdd(&rk[cl], 1);                // native ds_add_rtn_u32
        csr[start[cl] + r] =
            make_float2(__int_as_float(row), __uint_as_float((unsigned)(p >> 32)));
    }
}

// K3: xwh = bf16( (x @ W) * dis[row] ). 32 rows/block; runs after place_kernel
// (needs dis). Folding dis[row] here removes the per-edge dis gather entirely.
__global__ void __launch_bounds__(256) xw_kernel(
    const float* __restrict__ x, const float* __restrict__ W,
    const float* __restrict__ dis, __hip_bfloat16* __restrict__ xwh)
{
    __shared__ float sW[CH * CH];   // 16 KB
    __shared__ float sx[32][CH];    // 8 KB
    int t = threadIdx.x;
    for (int i = t; i < CH * CH; i += 256) sW[i] = W[i];
    for (int i = t; i < 32 * CH; i += 256)
        sx[i >> 6][i & 63] = x[(size_t)blockIdx.x * (32 * CH) + i];
    __syncthreads();
    int rr = t >> 6, cc = t & 63;
    float a[8] = {0.f, 0.f, 0.f, 0.f, 0.f, 0.f, 0.f, 0.f};
    for (int k = 0; k < CH; k += 4) {
        float w0 = sW[k * CH + cc],       w1 = sW[(k + 1) * CH + cc];
        float w2 = sW[(k + 2) * CH + cc], w3 = sW[(k + 3) * CH + cc];
#pragma unroll
        for (int j = 0; j < 8; j++) {
            float4 xv = *(const float4*)&sx[rr + 4 * j][k];
            a[j] = fmaf(xv.x, w0, a[j]);
            a[j] = fmaf(xv.y, w1, a[j]);
            a[j] = fmaf(xv.z, w2, a[j]);
            a[j] = fmaf(xv.w, w3, a[j]);
        }
    }
    int r0 = blockIdx.x * 32;
#pragma unroll
    for (int j = 0; j < 8; j++) {
        int r = r0 + rr + 4 * j;
        xwh[(size_t)r * CH + cc] = __float2bfloat16(a[j] * dis[r]);
    }
}

// K4: R0's harness-proven gather structure: one wave per node, lane = channel,
// register accumulation over the node's contiguous CSR slice, 4-edge ILP,
// then LN + SiLU + residual. No LDS, no barriers.
__global__ void __launch_bounds__(256) gather_finalize_kernel(
    const float2* __restrict__ csr, const int2* __restrict__ nrange,
    const float* __restrict__ dis, const __hip_bfloat16* __restrict__ xwh,
    const float* __restrict__ x, const float* __restrict__ b,
    const float* __restrict__ gamma, const float* __restrict__ beta,
    float* __restrict__ out)
{
    int t = threadIdx.x;
    int node = blockIdx.x * 4 + (t >> 6);
    int c = t & 63;
    int2 rg = nrange[node];
    int s = rg.x, en = rg.y;
    float acc = 0.0f;
    int i = s;
    if ((i & 1) && i < en) {
        float2 p = csr[i++];
        int r = __float_as_int(p.x);
        acc = fmaf(__bfloat162float(xwh[(size_t)r * CH + c]), p.y, acc);
    }
    for (; i + 3 < en; i += 4) {
        float4 q0 = *(const float4*)(csr + i);
        float4 q1 = *(const float4*)(csr + i + 2);
        int r0 = __float_as_int(q0.x), r1 = __float_as_int(q0.z);
        int r2 = __float_as_int(q1.x), r3 = __float_as_int(q1.z);
        acc = fmaf(__bfloat162float(xwh[(size_t)r0 * CH + c]), q0.y, acc);
        acc = fmaf(__bfloat162float(xwh[(size_t)r1 * CH + c]), q0.w, acc);
        acc = fmaf(__bfloat162float(xwh[(size_t)r2 * CH + c]), q1.y, acc);
        acc = fmaf(__bfloat162float(xwh[(size_t)r3 * CH + c]), q1.w, acc);
    }
    if (i + 1 < en) {
        float4 q0 = *(const float4*)(csr + i);
        int r0 = __float_as_int(q0.x), r1 = __float_as_int(q0.z);
        acc = fmaf(__bfloat162float(xwh[(size_t)r0 * CH + c]), q0.y, acc);
        acc = fmaf(__bfloat162float(xwh[(size_t)r1 * CH + c]), q0.w, acc);
        i += 2;
    }
    if (i < en) {
        float2 p = csr[i];
        int r = __float_as_int(p.x);
        acc = fmaf(__bfloat162float(xwh[(size_t)r * CH + c]), p.y, acc);
    }
    float hv = fmaf(acc, dis[node], b[c]);
    float ssum = hv;
#pragma unroll
    for (int off = 32; off; off >>= 1) ssum += __shfl_xor(ssum, off, 64);
    float mu = ssum * (1.0f / 64.0f);
    float d = hv - mu;
    float v2 = d * d;
#pragma unroll
    for (int off = 32; off; off >>= 1) v2 += __shfl_xor(v2, off, 64);
    float y = d * rsqrtf(v2 * (1.0f / 64.0f) + 1e-5f) * gamma[c] + beta[c];
    y *= sigm(y);
    size_t idx = (size_t)node * CH + c;
    out[idx] = y + x[idx];
}

extern "C" void kernel_launch(void* const* d_in, const int* in_sizes, int n_in,
                              void* d_out, int out_size, void* d_ws, size_t ws_size,
                              hipStream_t stream)
{
    const float* x     = (const float*)d_in[0];
    const int*   ei    = (const int*)d_in[1];
    const float* ea    = (const float*)d_in[2];
    const float* W     = (const float*)d_in[3];
    const float* b     = (const float*)d_in[4];
    const float* W1    = (const float*)d_in[5];
    const float* b1    = (const float*)d_in[6];
    const float* W2    = (const float*)d_in[7];
    const float* b2    = (const float*)d_in[8];
    const float* gamma = (const float*)d_in[9];
    const float* beta  = (const float*)d_in[10];
    float* out = (float*)d_out;

    // ws layout: binned u64[NBKT*BCAP] | csr f2[NBKT*BCAP] | xwh bf16[NN*CH]
    //            | nrange int2[NN] | dis f32[NN] | gcursor i32[NBKT+1 pad]
    unsigned long long* binned = (unsigned long long*)d_ws;
    float2* csr    = (float2*)(binned + (size_t)NBKT * BCAP);
    __hip_bfloat16* xwh = (__hip_bfloat16*)(csr + (size_t)NBKT * BCAP);
    int2*  nrange  = (int2*)(xwh + (size_t)NN * CH);
    float* dis     = (float*)(nrange + NN);
    int*   gcursor = (int*)(dis + NN);

    hipMemsetAsync(gcursor, 0, (NBKT + 1) * sizeof(int), stream);

    gate_bin_kernel<<<(EE + EPB - 1) / EPB, 512, 0, stream>>>(ea, W1, b1, W2, b2, ei,
                                                              gcursor, binned);
    place_kernel<<<NBKT, 256, 0, stream>>>(binned, gcursor, nrange, dis, csr);
    xw_kernel<<<NN / 32, 256, 0, stream>>>(x, W, dis, xwh);
    gather_finalize_kernel<<<NN / 4, 256, 0, stream>>>(csr, nrange, dis, xwh,
                                                       x, b, gamma, beta, out);
}